// Round 1
// baseline (365.068 us; speedup 1.0000x reference)
//
#include <hip/hip_runtime.h>
#include <hip/hip_bf16.h>

// SocialGNN: 2-layer GCN, N=100000 nodes, E=1600000 edges (+ self loops),
// feat 256 -> 128 (relu) -> 16.
//
// R10: agg1 feature-chunked for XCD-L2 residency. h1s/tbuf become chunk-major
// [8][n][16] bf16; chunk c (3.2 MB < 4 MB per-XCD L2) is processed only by
// blocks with blockIdx&7==c, which land on XCD c under round-robin dispatch.
// The 410 MB random gather stream turns from ~54% L2-hit (188 MB L2-miss
// traffic, agg1=64us) into ~all-hit; csr is re-read 8x (+45 MB, cheap).
// gemm1 epilogue + gemm2 tbuf reads re-addressed for the chunk-major layout.
// History: R2 -- never funnel E atomics into <1K addresses. R4 -- bf16
// intermediates halve gather traffic; error attenuated by dinv~0.24 twice per
// layer. R5/R8 -- agg1 plateau ~74us broken to <64us by 2 nodes/wave. R7 --
// per-wave-redundant MFMA operand streams from global = 2x regression.
// R8 -- 2-barrier-per-kstep LDS gemm1 stall-bound at 66us. R9 -- resident-B
// LDS gemm1 (64KB W1 in LDS once, barrier-free k-loop).

typedef __attribute__((ext_vector_type(8))) short short8;
typedef __attribute__((ext_vector_type(4))) float f32x4;

__device__ inline unsigned short f2bf(float f) {
    __hip_bfloat16 h = __float2bfloat16(f);
    return *(unsigned short*)&h;
}
__device__ inline float bf2f(unsigned short u) {
    unsigned int v = ((unsigned int)u) << 16;
    return *(float*)&v;
}

#define N_FEAT_IN 256
#define NBUCK 1024     // dst>>7; used buckets = ceil(n/128) = 782
#define NBINBLK 256    // partition blocks; bbc is [NBUCK][NBINBLK]

// ---------------- partition pass 1: per-(block,bucket) LDS histogram ----------------
__global__ __launch_bounds__(256) void k_bhist(const int* __restrict__ dst,
                                               int* __restrict__ bbc, int E, int chunk) {
    __shared__ int lcnt[NBUCK];
    for (int i = threadIdx.x; i < NBUCK; i += 256) lcnt[i] = 0;
    __syncthreads();
    int start = blockIdx.x * chunk;
    int end = min(start + chunk, E);
    for (int e = start + threadIdx.x; e < end; e += 256)
        atomicAdd(&lcnt[dst[e] >> 7], 1);
    __syncthreads();
    for (int i = threadIdx.x; i < NBUCK; i += 256)
        bbc[i * NBINBLK + blockIdx.x] = lcnt[i];
}

// ---- partition pass 2: per-bucket local exclusive scan across blocks + totals ----
__global__ __launch_bounds__(256) void k_bexscan(int* __restrict__ bbc,
                                                 int* __restrict__ btot) {
    __shared__ int ts[NBINBLK];
    int bucket = blockIdx.x;
    int t = threadIdx.x;
    int v = bbc[bucket * NBINBLK + t];
    ts[t] = v; __syncthreads();
    for (int off = 1; off < NBINBLK; off <<= 1) {
        int x = (t >= off) ? ts[t - off] : 0;
        __syncthreads();
        ts[t] += x;
        __syncthreads();
    }
    bbc[bucket * NBINBLK + t] = ts[t] - v;   // local exclusive (no base yet)
    if (t == NBINBLK - 1) btot[bucket] = ts[t];
}

// ---------------- bucket-total exclusive scan -> bucket bases ----------------
__global__ __launch_bounds__(1024) void k_bscan(const int* __restrict__ btot,
                                                int* __restrict__ bbase) {
    __shared__ int ts[NBUCK];
    int t = threadIdx.x;
    int v = btot[t];
    ts[t] = v; __syncthreads();
    for (int off = 1; off < NBUCK; off <<= 1) {
        int x = (t >= off) ? ts[t - off] : 0;
        __syncthreads();
        ts[t] += x;
        __syncthreads();
    }
    bbase[t] = ts[t] - v;  // exclusive
}

// ---------------- partition pass 3: binned write (24-bit packed) ----------------
// packed edge: bits 0-16 src (n<2^17), bits 17-23 dst&127.
__global__ __launch_bounds__(256) void k_bin2(const int* __restrict__ src,
                                              const int* __restrict__ dst,
                                              const int* __restrict__ bbc,
                                              const int* __restrict__ bbase,
                                              int* __restrict__ ebuf, int E, int chunk) {
    __shared__ int lcur[NBUCK];
    for (int i = threadIdx.x; i < NBUCK; i += 256)
        lcur[i] = bbc[i * NBINBLK + blockIdx.x] + bbase[i];
    __syncthreads();
    int start = blockIdx.x * chunk;
    int end = min(start + chunk, E);
    for (int e = start + threadIdx.x; e < end; e += 256) {
        int s = src[e], d = dst[e];
        int pos = atomicAdd(&lcur[d >> 7], 1);  // LDS atomic
        ebuf[pos] = s | ((d & 127) << 17);
    }
}

// ---- per-bucket counting sort: ebuf window -> csr; also row_ptr, dinv ----
__global__ __launch_bounds__(256) void k_sortb(const int* __restrict__ ebuf,
                                               const int* __restrict__ bbase,
                                               int* __restrict__ row_ptr,
                                               float* __restrict__ dinv,
                                               int* __restrict__ csr, int n, int E) {
    __shared__ int lcnt[128];
    __shared__ int lcur[128];
    int b = blockIdx.x;
    int node0 = b << 7;
    int nodes = min(128, n - node0);
    int t = threadIdx.x;
    int s_start = bbase[b];
    int s_end = bbase[b + 1];
    if (t < 128) lcnt[t] = 0;
    __syncthreads();
    for (int e = s_start + t; e < s_end; e += 256)
        atomicAdd(&lcnt[(ebuf[e] >> 17) & 127], 1);
    __syncthreads();
    int deg = (t < 128) ? lcnt[t] : 0;
    if (t < 128) lcur[t] = deg;
    __syncthreads();
    for (int off = 1; off < 128; off <<= 1) {
        int x = 0;
        if (t < 128 && t >= off) x = lcur[t - off];
        __syncthreads();
        if (t < 128) lcur[t] += x;
        __syncthreads();
    }
    if (t < 128) {
        int excl = s_start + lcur[t] - deg;
        if (t < nodes) {
            row_ptr[node0 + t] = excl;
            dinv[node0 + t] = rsqrtf((float)deg + 1.0f);  // +1 self-loop
        }
        lcur[t] = excl;  // write cursor
    }
    if (b == 0 && t == 0) row_ptr[n] = E;
    __syncthreads();
    for (int e = s_start + t; e < s_end; e += 256) {
        int p = ebuf[e];
        int pos = atomicAdd(&lcur[(p >> 17) & 127], 1);  // LDS atomic
        csr[pos] = p & 0x1FFFF;
    }
}

// ------ W1 [256][128] f32 -> W1t packed [kq 0..31][n 0..127][j 0..7] bf16 ------
// element (n, k=kq*8+j) lives at W1t[kq*1024 + n*8 + j].
__global__ void k_prep(const float* __restrict__ W1, unsigned short* __restrict__ W1t) {
    int nn = blockIdx.x;          // 0..127
    int k = threadIdx.x;          // 0..255
    int kq = k >> 3, j = k & 7;
    W1t[kq * 1024 + nn * 8 + j] = f2bf(W1[k * 128 + nn]);
}

// ---------------- GEMM1 (MFMA, resident-B): X[M,256]f32 @ W1 -> h1s bf16, *dinv -----
// W1 (64 KB bf16, kq-major) loaded to LDS once; k-loop barrier-free: per lane
// 2 coalesced float4 A loads from X + cvt + 8 ds_read_b128 + 8 MFMA.
// R10: epilogue stores CHUNK-MAJOR h1s [8][M][16] (chunk = col>>4) for agg1.
__global__ __launch_bounds__(256) void k_gemm1(const float* __restrict__ X,
                                               const unsigned short* __restrict__ W1t,
                                               const float* __restrict__ dinv,
                                               unsigned short* __restrict__ h1s, int M) {
    __shared__ unsigned short Bs[32768];   // 64 KB, [kq][n][8]
    const int tid = threadIdx.x;
    const int wv = tid >> 6;
    const int lane = tid & 63;
    const int hq = lane >> 4;       // quad 0..3
    const int l15 = lane & 15;
    const int block_row = blockIdx.x * 64;

    // flat 64 KB memcpy global->LDS (uint4 = 16 B per thread per iter)
#pragma unroll
    for (int i = 0; i < 16; ++i)
        ((uint4*)Bs)[tid + i * 256] = ((const uint4*)W1t)[tid + i * 256];
    __syncthreads();

    int arow = block_row + wv * 16 + l15;
    if (arow >= M) arow = M - 1;                       // clamp; stores masked
    const float* xp = X + (size_t)arow * 256 + hq * 8;

    f32x4 acc[8];
#pragma unroll
    for (int c = 0; c < 8; ++c) acc[c] = (f32x4){0.f, 0.f, 0.f, 0.f};

#pragma unroll
    for (int ks = 0; ks < 8; ++ks) {                   // k0 = 32*ks
        float4 a0 = *(const float4*)(xp + 32 * ks);
        float4 a1 = *(const float4*)(xp + 32 * ks + 4);
        short8 a;
        a[0] = (short)f2bf(a0.x); a[1] = (short)f2bf(a0.y);
        a[2] = (short)f2bf(a0.z); a[3] = (short)f2bf(a0.w);
        a[4] = (short)f2bf(a1.x); a[5] = (short)f2bf(a1.y);
        a[6] = (short)f2bf(a1.z); a[7] = (short)f2bf(a1.w);
        const unsigned short* bp = Bs + (ks * 4 + hq) * 1024 + l15 * 8;
#pragma unroll
        for (int c = 0; c < 8; ++c) {
            short8 b = *(const short8*)(bp + c * 128);
            acc[c] = __builtin_amdgcn_mfma_f32_16x16x32_bf16(a, b, acc[c], 0, 0, 0);
        }
    }
    // D: row = 16wv + hq*4 + r, col = c*16 + l15 -> chunk-major store
    const size_t M16 = (size_t)M * 16;
#pragma unroll
    for (int r = 0; r < 4; ++r) {
        int row = block_row + 16 * wv + hq * 4 + r;
        if (row < M) {
            float dv = dinv[row];
#pragma unroll
            for (int c = 0; c < 8; ++c) {
                h1s[(size_t)c * M16 + (size_t)row * 16 + l15] = f2bf(acc[c][r] * dv);
            }
        }
    }
}

// ---------------- agg1 (R10): feature-chunked, XCD-L2-resident gather ----------------
// h1s/tbuf chunk-major [8][n][16] bf16. chunk c = blockIdx&7 -> XCD c under
// round-robin dispatch; the 3.2 MB chunk slice stays resident in that XCD's
// 4 MB L2, so the per-edge gathers are L2 hits. 4 lanes/node, uint2 = 4 feats
// per lane; 4-deep unrolled gather loop for MLP; per-group (node) loop is
// divergence-masked, no clamped over-fetch.
__global__ __launch_bounds__(256) void k_agg1(const unsigned short* __restrict__ h1s,
                                              const int* __restrict__ rp,
                                              const int* __restrict__ csr,
                                              const float* __restrict__ dinv,
                                              const float* __restrict__ b1,
                                              unsigned short* __restrict__ tbuf, int n) {
    const int c = blockIdx.x & 7;            // feature chunk == XCD id
    const int nb = blockIdx.x >> 3;
    const int node = nb * 64 + (threadIdx.x >> 2);
    const int q = threadIdx.x & 3;           // lane within 4-lane node group
    if (node >= n) return;
    const uint2* hv = (const uint2*)(h1s + (size_t)c * n * 16);  // [n][4] uint2
    uint2 us = hv[(size_t)node * 4 + q];     // self (already *dinv)
    float a0 = bf2f((unsigned short)(us.x & 0xffff));
    float a1 = bf2f((unsigned short)(us.x >> 16));
    float a2 = bf2f((unsigned short)(us.y & 0xffff));
    float a3 = bf2f((unsigned short)(us.y >> 16));
    int e = rp[node];
    const int end = rp[node + 1];
    for (; e + 4 <= end; e += 4) {
        int s0 = csr[e + 0], s1 = csr[e + 1], s2 = csr[e + 2], s3 = csr[e + 3];
        uint2 u0 = hv[(size_t)s0 * 4 + q];
        uint2 u1 = hv[(size_t)s1 * 4 + q];
        uint2 u2 = hv[(size_t)s2 * 4 + q];
        uint2 u3 = hv[(size_t)s3 * 4 + q];
        a0 += (bf2f((unsigned short)(u0.x & 0xffff)) + bf2f((unsigned short)(u1.x & 0xffff))) +
              (bf2f((unsigned short)(u2.x & 0xffff)) + bf2f((unsigned short)(u3.x & 0xffff)));
        a1 += (bf2f((unsigned short)(u0.x >> 16)) + bf2f((unsigned short)(u1.x >> 16))) +
              (bf2f((unsigned short)(u2.x >> 16)) + bf2f((unsigned short)(u3.x >> 16)));
        a2 += (bf2f((unsigned short)(u0.y & 0xffff)) + bf2f((unsigned short)(u1.y & 0xffff))) +
              (bf2f((unsigned short)(u2.y & 0xffff)) + bf2f((unsigned short)(u3.y & 0xffff)));
        a3 += (bf2f((unsigned short)(u0.y >> 16)) + bf2f((unsigned short)(u1.y >> 16))) +
              (bf2f((unsigned short)(u2.y >> 16)) + bf2f((unsigned short)(u3.y >> 16)));
    }
    for (; e < end; ++e) {
        uint2 u = hv[(size_t)csr[e] * 4 + q];
        a0 += bf2f((unsigned short)(u.x & 0xffff));
        a1 += bf2f((unsigned short)(u.x >> 16));
        a2 += bf2f((unsigned short)(u.y & 0xffff));
        a3 += bf2f((unsigned short)(u.y >> 16));
    }
    float dv = dinv[node];
    float4 bb = *(const float4*)(b1 + c * 16 + q * 4);
    float t0 = fmaxf(dv * a0 + bb.x, 0.0f);
    float t1 = fmaxf(dv * a1 + bb.y, 0.0f);
    float t2 = fmaxf(dv * a2 + bb.z, 0.0f);
    float t3 = fmaxf(dv * a3 + bb.w, 0.0f);
    uint2 packed;
    packed.x = (unsigned int)f2bf(t0) | ((unsigned int)f2bf(t1) << 16);
    packed.y = (unsigned int)f2bf(t2) | ((unsigned int)f2bf(t3) << 16);
    ((uint2*)tbuf)[(size_t)c * n * 4 + (size_t)node * 4 + q] = packed;
}

// ---------------- GEMM2: tbuf (chunk-major [8][n][16] bf16) @ W2 -> h2s, *dinv -------
__global__ __launch_bounds__(256) void k_gemm2(const unsigned short* __restrict__ tbuf,
                                               const float* __restrict__ W2,
                                               const float* __restrict__ dinv,
                                               unsigned short* __restrict__ h2s, int n) {
    __shared__ float w2s[128 * 16];
    for (int i = threadIdx.x; i < 2048; i += 256) w2s[i] = W2[i];
    __syncthreads();
    int gid = blockIdx.x * 256 + threadIdx.x;
    int node = gid >> 4;
    int o = gid & 15;
    if (node >= n) return;
    const uint4* tv = (const uint4*)tbuf;    // chunk slice: node -> 2 uint4 (32 B)
    float acc = 0.0f;
#pragma unroll
    for (int cc = 0; cc < 8; ++cc) {
        size_t base = ((size_t)cc * n + node) * 2;
        uint4 u0 = tv[base];
        uint4 u1 = tv[base + 1];
        int k = cc * 16;
        acc += __uint_as_float(u0.x << 16) * w2s[(k + 0) * 16 + o];
        acc += __uint_as_float(u0.x & 0xffff0000u) * w2s[(k + 1) * 16 + o];
        acc += __uint_as_float(u0.y << 16) * w2s[(k + 2) * 16 + o];
        acc += __uint_as_float(u0.y & 0xffff0000u) * w2s[(k + 3) * 16 + o];
        acc += __uint_as_float(u0.z << 16) * w2s[(k + 4) * 16 + o];
        acc += __uint_as_float(u0.z & 0xffff0000u) * w2s[(k + 5) * 16 + o];
        acc += __uint_as_float(u0.w << 16) * w2s[(k + 6) * 16 + o];
        acc += __uint_as_float(u0.w & 0xffff0000u) * w2s[(k + 7) * 16 + o];
        acc += __uint_as_float(u1.x << 16) * w2s[(k + 8) * 16 + o];
        acc += __uint_as_float(u1.x & 0xffff0000u) * w2s[(k + 9) * 16 + o];
        acc += __uint_as_float(u1.y << 16) * w2s[(k + 10) * 16 + o];
        acc += __uint_as_float(u1.y & 0xffff0000u) * w2s[(k + 11) * 16 + o];
        acc += __uint_as_float(u1.z << 16) * w2s[(k + 12) * 16 + o];
        acc += __uint_as_float(u1.z & 0xffff0000u) * w2s[(k + 13) * 16 + o];
        acc += __uint_as_float(u1.w << 16) * w2s[(k + 14) * 16 + o];
        acc += __uint_as_float(u1.w & 0xffff0000u) * w2s[(k + 15) * 16 + o];
    }
    h2s[(size_t)node * 16 + o] = f2bf(acc * dinv[node]);
}

// ---------------- agg2: 4 lanes/node, uint2 (4 bf16 feats) per lane ----------------
__global__ __launch_bounds__(256) void k_agg2(const unsigned short* __restrict__ h2s,
                                              const int* __restrict__ rp,
                                              const int* __restrict__ csr,
                                              const float* __restrict__ dinv,
                                              const float* __restrict__ b2,
                                              float* __restrict__ out, int n) {
    int wid = (blockIdx.x * 256 + threadIdx.x) >> 6;
    int lane = threadIdx.x & 63;
    int slot = lane >> 2;
    int q = lane & 3;
    int node = wid * 16 + slot;
    bool valid = node < n;
    int nodec = valid ? node : n - 1;
    int start = rp[nodec];
    int deg = rp[nodec + 1] - start;
    int mx = deg;
#pragma unroll
    for (int off = 4; off < 64; off <<= 1) mx = max(mx, __shfl_xor(mx, off));
    uint2 us = *(const uint2*)(h2s + ((unsigned)nodec << 4) + q * 4);
    float a0 = bf2f((unsigned short)(us.x & 0xffff));
    float a1 = bf2f((unsigned short)(us.x >> 16));
    float a2 = bf2f((unsigned short)(us.y & 0xffff));
    float a3 = bf2f((unsigned short)(us.y >> 16));
    int clampi = deg > 0 ? deg - 1 : 0;
    int e = 0;
    for (; e + 2 <= mx; e += 2) {
        int s0 = csr[start + min(e, clampi)];
        int s1 = csr[start + min(e + 1, clampi)];
        uint2 u0 = *(const uint2*)(h2s + ((unsigned)s0 << 4) + q * 4);
        uint2 u1 = *(const uint2*)(h2s + ((unsigned)s1 << 4) + q * 4);
        if (e < deg) {
            a0 += bf2f((unsigned short)(u0.x & 0xffff));
            a1 += bf2f((unsigned short)(u0.x >> 16));
            a2 += bf2f((unsigned short)(u0.y & 0xffff));
            a3 += bf2f((unsigned short)(u0.y >> 16));
        }
        if (e + 1 < deg) {
            a0 += bf2f((unsigned short)(u1.x & 0xffff));
            a1 += bf2f((unsigned short)(u1.x >> 16));
            a2 += bf2f((unsigned short)(u1.y & 0xffff));
            a3 += bf2f((unsigned short)(u1.y >> 16));
        }
    }
    if (e < mx && e < deg) {
        int s = csr[start + e];
        uint2 u = *(const uint2*)(h2s + ((unsigned)s << 4) + q * 4);
        a0 += bf2f((unsigned short)(u.x & 0xffff));
        a1 += bf2f((unsigned short)(u.x >> 16));
        a2 += bf2f((unsigned short)(u.y & 0xffff));
        a3 += bf2f((unsigned short)(u.y >> 16));
    }
    if (valid) {
        float dv = dinv[node];
        float4 bb = *(const float4*)(b2 + q * 4);
        float4 o4 = make_float4(dv * a0 + bb.x, dv * a1 + bb.y,
                                dv * a2 + bb.z, dv * a3 + bb.w);
        *(float4*)(out + ((unsigned)node << 4) + q * 4) = o4;
    }
}

extern "C" void kernel_launch(void* const* d_in, const int* in_sizes, int n_in,
                              void* d_out, int out_size, void* d_ws, size_t ws_size,
                              hipStream_t stream) {
    const float* X  = (const float*)d_in[0];
    const int*   ei = (const int*)d_in[1];
    const float* W1 = (const float*)d_in[2];
    const float* b1 = (const float*)d_in[3];
    const float* W2 = (const float*)d_in[4];
    const float* b2 = (const float*)d_in[5];
    float* out = (float*)d_out;

    const int n = in_sizes[0] / N_FEAT_IN;   // 100000
    const int E = in_sizes[1] / 2;           // 1600000
    const int* src = ei;
    const int* dst = ei + E;

    char* ws = (char*)d_ws;
    size_t off = 0;
    auto alloc = [&](size_t bytes) -> char* {
        char* p = ws + off;
        off = (off + bytes + 255) & ~(size_t)255;
        return p;
    };
    float*          dinv    = (float*)alloc((size_t)n * 4);
    int*            row_ptr = (int*)alloc((size_t)(n + 1) * 4);
    int*            bbc     = (int*)alloc((size_t)NBUCK * NBINBLK * 4);  // 1 MB
    int*            btot    = (int*)alloc(NBUCK * 4);
    int*            bbase   = (int*)alloc((NBUCK + 1) * 4);
    int*            csr     = (int*)alloc((size_t)E * 4);
    int*            ebuf    = (int*)alloc((size_t)E * 4);                // 6.4 MB packed
    unsigned short* W1t     = (unsigned short*)alloc(128 * 256 * 2);     // 64 KB packed
    unsigned short* h1s     = (unsigned short*)alloc((size_t)n * 128 * 2);  // chunk-major [8][n][16]
    unsigned short* tbuf    = (unsigned short*)alloc((size_t)n * 128 * 2);  // chunk-major [8][n][16]
    unsigned short* h2s     = (unsigned short*)alloc((size_t)n * 16 * 2);
    (void)ws_size;

    const int NBK = (n + 127) / 128;         // 782 used buckets
    const int chunk = (E + NBINBLK - 1) / NBINBLK;

    k_bhist<<<NBINBLK, 256, 0, stream>>>(dst, bbc, E, chunk);
    k_bexscan<<<NBUCK, 256, 0, stream>>>(bbc, btot);
    k_bscan<<<1, NBUCK, 0, stream>>>(btot, bbase);
    k_bin2<<<NBINBLK, 256, 0, stream>>>(src, dst, bbc, bbase, ebuf, E, chunk);
    k_sortb<<<NBK, 256, 0, stream>>>(ebuf, bbase, row_ptr, dinv, csr, n, E);

    k_prep<<<128, 256, 0, stream>>>(W1, W1t);
    k_gemm1<<<(n + 63) / 64, 256, 0, stream>>>(X, W1t, dinv, h1s, n);
    k_agg1<<<((n + 63) / 64) * 8, 256, 0, stream>>>(h1s, row_ptr, csr, dinv, b1, tbuf, n);
    k_gemm2<<<((size_t)n * 16 + 255) / 256, 256, 0, stream>>>(tbuf, W2, dinv, h2s, n);
    k_agg2<<<(n + 63) / 64, 256, 0, stream>>>(h2s, row_ptr, csr, dinv, b2, out, n);
}